// Round 1
// baseline (2992.093 us; speedup 1.0000x reference)
//
#include <hip/hip_runtime.h>
#include <hip/hip_bf16.h>

#define HID 128
#define SEQ 2048
#define BATCH 64
#define NOUT 512

typedef __attribute__((ext_vector_type(8))) short bf16x8;
typedef __attribute__((ext_vector_type(4))) float f32x4;

__device__ __forceinline__ short f2bf(float f) {
    unsigned u = __float_as_uint(f);
    unsigned r = u + 0x7fffu + ((u >> 16) & 1u);   // RNE
    return (short)(r >> 16);
}

__device__ __forceinline__ float fast_sigmoid(float x) {
    return 1.0f / (1.0f + __expf(-x));
}

__device__ __forceinline__ float fast_tanh(float x) {
    // tanh(x) = 1 - 2/(e^{2x}+1); handles +-inf correctly
    return 1.0f - 2.0f / (__expf(2.0f * x) + 1.0f);
}

// One workgroup per batch element. 384 threads: thread j owns row j of W_hh
// (128 f32 in VGPRs, fully unrolled). h lives in LDS; gh exchanged via LDS.
__global__ __launch_bounds__(384, 2) void gru_seq(
    const float* __restrict__ latent,   // [BATCH][HID]
    const float* __restrict__ W_hh,     // [3*HID][HID]
    const float* __restrict__ b_ih,     // [3*HID]
    const float* __restrict__ b_hh,     // [3*HID]
    float* __restrict__ hs)             // [BATCH][SEQ][HID]
{
    const int b = blockIdx.x;
    const int j = threadIdx.x;          // 0..383

    __shared__ __align__(16) float h_s[HID];
    __shared__ float gh_s[3 * HID];

    // Preload W_hh row j into registers (fully unrolled -> stays in VGPRs)
    float w[HID];
    const float4* wrow = (const float4*)(W_hh + j * HID);
    #pragma unroll
    for (int k4 = 0; k4 < HID / 4; k4++) {
        float4 v = wrow[k4];
        w[4 * k4 + 0] = v.x; w[4 * k4 + 1] = v.y;
        w[4 * k4 + 2] = v.z; w[4 * k4 + 3] = v.w;
    }
    const float bhh = b_hh[j];
    float bir = 0.f, biz = 0.f, bin = 0.f;
    if (j < HID) {
        bir = b_ih[j];
        biz = b_ih[HID + j];
        bin = b_ih[2 * HID + j];
        h_s[j] = latent[b * HID + j];
    }
    __syncthreads();

    float* out_row = hs + (size_t)b * SEQ * HID;

    for (int t = 0; t < SEQ; t++) {
        // g_j = dot(h, W_hh[j,:]) + b_hh[j]; 4 accumulators for ILP
        float g0 = 0.f, g1 = 0.f, g2 = 0.f, g3 = 0.f;
        const float4* h4 = (const float4*)h_s;
        #pragma unroll
        for (int k4 = 0; k4 < HID / 4; k4++) {
            float4 hv = h4[k4];               // wave-uniform broadcast read
            g0 = fmaf(hv.x, w[4 * k4 + 0], g0);
            g1 = fmaf(hv.y, w[4 * k4 + 1], g1);
            g2 = fmaf(hv.z, w[4 * k4 + 2], g2);
            g3 = fmaf(hv.w, w[4 * k4 + 3], g3);
        }
        gh_s[j] = (g0 + g1) + (g2 + g3) + bhh;
        __syncthreads();

        if (j < HID) {
            float r  = fast_sigmoid(bir + gh_s[j]);
            float z  = fast_sigmoid(biz + gh_s[HID + j]);
            float n  = fast_tanh(bin + r * gh_s[2 * HID + j]);
            float hn = (1.0f - z) * n + z * h_s[j];
            h_s[j] = hn;
            out_row[t * HID + j] = hn;
        }
        __syncthreads();
    }
}

// Projection: out[row][o] = sum_k hs[row][k] * fc_W[o][k] + fc_b[o]
// M = BATCH*SEQ = 131072, N = 512, K = 128. bf16 MFMA 16x16x32.
// Each wave: 32 rows (2 row-tiles), loops over all 32 col-tiles.
// WG = 4 waves = 128 rows. Grid = 1024 blocks.
__global__ __launch_bounds__(256) void proj_mfma(
    const float* __restrict__ hs,      // [M][128]
    const float* __restrict__ fc_W,    // [512][128]  (= B^T layout, perfect)
    const float* __restrict__ fc_b,    // [512]
    float* __restrict__ out)           // [M][512]
{
    const int lane = threadIdx.x & 63;
    const int wave = threadIdx.x >> 6;
    const int m    = lane & 15;        // row-in-tile for A, col for C/D
    const int quad = lane >> 4;

    const long r0 = ((long)blockIdx.x * 4 + wave) * 32;

    // A-fragments: 2 row-tiles x 4 k-chunks, held in registers
    bf16x8 afrag[2][4];
    #pragma unroll
    for (int rt = 0; rt < 2; rt++) {
        #pragma unroll
        for (int q = 0; q < 4; q++) {
            const float* p = hs + (r0 + rt * 16 + m) * HID + q * 32 + quad * 8;
            float4 v0 = ((const float4*)p)[0];
            float4 v1 = ((const float4*)p)[1];
            bf16x8 a;
            a[0] = f2bf(v0.x); a[1] = f2bf(v0.y); a[2] = f2bf(v0.z); a[3] = f2bf(v0.w);
            a[4] = f2bf(v1.x); a[5] = f2bf(v1.y); a[6] = f2bf(v1.z); a[7] = f2bf(v1.w);
            afrag[rt][q] = a;
        }
    }

    for (int ct = 0; ct < 32; ct++) {
        f32x4 acc0 = {0.f, 0.f, 0.f, 0.f};
        f32x4 acc1 = {0.f, 0.f, 0.f, 0.f};
        #pragma unroll
        for (int q = 0; q < 4; q++) {
            const float* p = fc_W + (ct * 16 + m) * HID + q * 32 + quad * 8;
            float4 v0 = ((const float4*)p)[0];
            float4 v1 = ((const float4*)p)[1];
            bf16x8 bb;
            bb[0] = f2bf(v0.x); bb[1] = f2bf(v0.y); bb[2] = f2bf(v0.z); bb[3] = f2bf(v0.w);
            bb[4] = f2bf(v1.x); bb[5] = f2bf(v1.y); bb[6] = f2bf(v1.z); bb[7] = f2bf(v1.w);
            acc0 = __builtin_amdgcn_mfma_f32_16x16x32_bf16(afrag[0][q], bb, acc0, 0, 0, 0);
            acc1 = __builtin_amdgcn_mfma_f32_16x16x32_bf16(afrag[1][q], bb, acc1, 0, 0, 0);
        }
        const int col = ct * 16 + m;
        const float bias = fc_b[col];
        #pragma unroll
        for (int reg = 0; reg < 4; reg++) {
            const int row_in = quad * 4 + reg;
            out[(r0 + row_in) * NOUT + col]      = acc0[reg] + bias;
            out[(r0 + 16 + row_in) * NOUT + col] = acc1[reg] + bias;
        }
    }
}

extern "C" void kernel_launch(void* const* d_in, const int* in_sizes, int n_in,
                              void* d_out, int out_size, void* d_ws, size_t ws_size,
                              hipStream_t stream) {
    const float* latent = (const float*)d_in[0];   // (64,128)
    const float* W_hh   = (const float*)d_in[1];   // (384,128)
    const float* b_ih   = (const float*)d_in[2];   // (384,)
    const float* b_hh   = (const float*)d_in[3];   // (384,)
    const float* fc_W   = (const float*)d_in[4];   // (512,128)
    const float* fc_b   = (const float*)d_in[5];   // (512,)
    float* out = (float*)d_out;                    // (64,2048,512)
    float* hs  = (float*)d_ws;                     // (64,2048,128) scratch

    gru_seq<<<BATCH, 384, 0, stream>>>(latent, W_hh, b_ih, b_hh, hs);

    const int M = BATCH * SEQ;                     // 131072
    proj_mfma<<<M / 128, 256, 0, stream>>>(hs, fc_W, fc_b, out);
}

// Round 2
// 1889.556 us; speedup vs baseline: 1.5835x; 1.5835x over previous
//
#include <hip/hip_runtime.h>
#include <hip/hip_bf16.h>

#define HID 128
#define SEQ 2048
#define BATCH 64
#define NOUT 512

typedef __attribute__((ext_vector_type(8))) short bf16x8;
typedef __attribute__((ext_vector_type(4))) float f32x4;

__device__ __forceinline__ short f2bf(float f) {
    unsigned u = __float_as_uint(f);
    unsigned r = u + 0x7fffu + ((u >> 16) & 1u);   // RNE
    return (short)(r >> 16);
}

__device__ __forceinline__ float fast_sigmoid(float x) {
    return 1.0f / (1.0f + __expf(-x));
}

__device__ __forceinline__ float fast_tanh(float x) {
    return 1.0f - 2.0f / (__expf(2.0f * x) + 1.0f);
}

// ---------------------------------------------------------------------------
// GRU recurrence. One block per batch element (64 blocks -> 64 CUs).
// 768 threads = 12 waves. Thread tid owns HALF a W_hh row:
//   row = tid mod 384, half = tid / 384  (wave-uniform half => LDS h reads
//   are full 64-lane broadcasts, conflict-free).
// 64 weights/thread stay in VGPRs (v1's 128/thread spilled: VGPR_Count=100,
// FETCH 828MB of scratch traffic). Partials meet in LDS; 128 gate threads
// finish sigmoid/tanh/update and emit h as bf16 for the MFMA projection.
// ---------------------------------------------------------------------------
__global__ __launch_bounds__(768, 3) void gru_seq(
    const float* __restrict__ latent,   // [BATCH][HID]
    const float* __restrict__ W_hh,     // [3*HID][HID]
    const float* __restrict__ b_ih,     // [3*HID]
    const float* __restrict__ b_hh,     // [3*HID]
    __hip_bfloat16* __restrict__ hs)    // [BATCH][SEQ][HID]  (bf16)
{
    const int b   = blockIdx.x;
    const int tid = threadIdx.x;                 // 0..767
    const int half = (tid >= 384) ? 1 : 0;
    const int row  = tid - half * 384;           // 0..383

    __shared__ __align__(16) float h_s[HID];
    __shared__ float partial[768];

    // 64 weights per thread -> VGPRs (no spill)
    float w[64];
    {
        const float4* wp = (const float4*)(W_hh + row * HID + half * 64);
        #pragma unroll
        for (int k4 = 0; k4 < 16; k4++) {
            float4 v = wp[k4];
            w[4 * k4 + 0] = v.x; w[4 * k4 + 1] = v.y;
            w[4 * k4 + 2] = v.z; w[4 * k4 + 3] = v.w;
        }
    }
    const float bhh = (half == 0) ? b_hh[row] : 0.0f;

    float bir = 0.f, biz = 0.f, bin = 0.f;
    if (tid < HID) {
        bir = b_ih[tid];
        biz = b_ih[HID + tid];
        bin = b_ih[2 * HID + tid];
        h_s[tid] = latent[b * HID + tid];
    }
    __syncthreads();

    __hip_bfloat16* out_row = hs + (size_t)b * SEQ * HID;

    for (int t = 0; t < SEQ; t++) {
        // partial dot over this thread's 64-wide slice of h
        float g0 = 0.f, g1 = 0.f, g2 = 0.f, g3 = 0.f;
        const float4* h4 = (const float4*)h_s + half * 16;
        #pragma unroll
        for (int k4 = 0; k4 < 16; k4++) {
            float4 hv = h4[k4];                  // wave-uniform broadcast
            g0 = fmaf(hv.x, w[4 * k4 + 0], g0);
            g1 = fmaf(hv.y, w[4 * k4 + 1], g1);
            g2 = fmaf(hv.z, w[4 * k4 + 2], g2);
            g3 = fmaf(hv.w, w[4 * k4 + 3], g3);
        }
        partial[tid] = (g0 + g1) + (g2 + g3) + bhh;
        __syncthreads();

        if (tid < HID) {
            float gr = partial[tid]           + partial[384 + tid];
            float gz = partial[HID + tid]     + partial[384 + HID + tid];
            float gn = partial[2 * HID + tid] + partial[384 + 2 * HID + tid];
            float r  = fast_sigmoid(bir + gr);
            float z  = fast_sigmoid(biz + gz);
            float n  = fast_tanh(bin + r * gn);
            float hn = (1.0f - z) * n + z * h_s[tid];
            h_s[tid] = hn;
            out_row[t * HID + tid] = __hip_bfloat16(__builtin_bit_cast(__hip_bfloat16_raw, (unsigned short)f2bf(hn)));
        }
        __syncthreads();
    }
}

// ---------------------------------------------------------------------------
// Repack fc_W (f32 [512][128]) into bf16 MFMA B-fragment order:
//   wfrag[((ct*4 + q)*64 + lane)*8 + j] = bf16(fc_W[ct*16 + (lane&15)]
//                                                  [q*32 + (lane>>4)*8 + j])
// so the proj kernel's B loads are lane-contiguous 16B (perfect coalescing,
// zero conversion VALU in the hot loop).
// ---------------------------------------------------------------------------
__global__ void wprep(const float* __restrict__ fc_W,
                      __hip_bfloat16* __restrict__ wfrag)
{
    int t = blockIdx.x * 256 + threadIdx.x;      // 0..65535
    int j    = t & 7;
    int lane = (t >> 3) & 63;
    int q    = (t >> 9) & 3;
    int ct   = t >> 11;
    int n = ct * 16 + (lane & 15);
    int k = q * 32 + (lane >> 4) * 8 + j;
    unsigned short v = (unsigned short)f2bf(fc_W[n * HID + k]);
    wfrag[t] = __builtin_bit_cast(__hip_bfloat16, v);
}

// ---------------------------------------------------------------------------
// Projection: out[row][o] = sum_k hs[row][k] * fc_W[o][k] + fc_b[o]
// M = 131072, N = 512, K = 128. bf16 MFMA 16x16x32.
// A comes straight from bf16 hs (16B/lane aligned loads, no cvt);
// B comes from the fragment-ordered wfrag (lane-contiguous 16B loads).
// Each wave: 32 rows x all 512 cols. WG = 4 waves = 128 rows, 1024 blocks.
// ---------------------------------------------------------------------------
__global__ __launch_bounds__(256) void proj_mfma(
    const __hip_bfloat16* __restrict__ hsb,    // [M][128] bf16
    const __hip_bfloat16* __restrict__ wfrag,  // fragment-ordered [32][4][64][8]
    const float* __restrict__ fc_b,            // [512]
    float* __restrict__ out)                   // [M][512] f32
{
    const int lane = threadIdx.x & 63;
    const int wave = threadIdx.x >> 6;
    const int m    = lane & 15;
    const int quad = lane >> 4;

    const long r0 = ((long)blockIdx.x * 4 + wave) * 32;

    bf16x8 afrag[2][4];
    #pragma unroll
    for (int rt = 0; rt < 2; rt++) {
        #pragma unroll
        for (int q = 0; q < 4; q++) {
            const __hip_bfloat16* p =
                hsb + (r0 + rt * 16 + m) * HID + q * 32 + quad * 8;
            afrag[rt][q] = *(const bf16x8*)p;   // 16B aligned
        }
    }

    for (int ct = 0; ct < 32; ct++) {
        f32x4 acc0 = {0.f, 0.f, 0.f, 0.f};
        f32x4 acc1 = {0.f, 0.f, 0.f, 0.f};
        #pragma unroll
        for (int q = 0; q < 4; q++) {
            bf16x8 bb = *(const bf16x8*)(wfrag + ((ct * 4 + q) * 64 + lane) * 8);
            acc0 = __builtin_amdgcn_mfma_f32_16x16x32_bf16(afrag[0][q], bb, acc0, 0, 0, 0);
            acc1 = __builtin_amdgcn_mfma_f32_16x16x32_bf16(afrag[1][q], bb, acc1, 0, 0, 0);
        }
        const int col = ct * 16 + m;
        const float bias = fc_b[col];
        #pragma unroll
        for (int reg = 0; reg < 4; reg++) {
            const int row_in = quad * 4 + reg;
            out[(r0 + row_in) * NOUT + col]      = acc0[reg] + bias;
            out[(r0 + 16 + row_in) * NOUT + col] = acc1[reg] + bias;
        }
    }
}

extern "C" void kernel_launch(void* const* d_in, const int* in_sizes, int n_in,
                              void* d_out, int out_size, void* d_ws, size_t ws_size,
                              hipStream_t stream) {
    const float* latent = (const float*)d_in[0];   // (64,128)
    const float* W_hh   = (const float*)d_in[1];   // (384,128)
    const float* b_ih   = (const float*)d_in[2];   // (384,)
    const float* b_hh   = (const float*)d_in[3];   // (384,)
    const float* fc_W   = (const float*)d_in[4];   // (512,128)
    const float* fc_b   = (const float*)d_in[5];   // (512,)
    float* out = (float*)d_out;                    // (64,2048,512)

    __hip_bfloat16* hsb   = (__hip_bfloat16*)d_ws;                   // 33.5 MB
    __hip_bfloat16* wfrag = (__hip_bfloat16*)((char*)d_ws + (size_t)BATCH * SEQ * HID * 2);

    wprep<<<256, 256, 0, stream>>>(fc_W, wfrag);
    gru_seq<<<BATCH, 768, 0, stream>>>(latent, W_hh, b_ih, b_hh, hsb);

    const int M = BATCH * SEQ;                     // 131072
    proj_mfma<<<M / 128, 256, 0, stream>>>(hsb, wfrag, fc_b, out);
}